// Round 23
// baseline (55.568 us; speedup 1.0000x reference)
//
#include <hip/hip_runtime.h>

#define NPTS 4096
#define NEDGE 8064
#define M0f 0.05f
#define KMAXD2 7938
#define IDCAP 90          // basin-id clamp; triangular pair table needs IDCAP*(IDCAP-1)/2 <= 4096
#define SORTCAP 512
#define PAIRCAP 160
#define MSTCAP 128        // collected edges = #merges <= IDCAP-1 = 89 (distinct; mutual-min collects once)

typedef unsigned long long u64;

__device__ inline float waveSum(float x) {
  for (int m = 32; m >= 1; m >>= 1) x += __shfl_xor(x, m);
  return x;
}

__device__ inline int isqrt_i(int x) {  // exact floor sqrt for 0 <= x < 2^20
  int r = (int)sqrtf((float)x);
  if ((r + 1) * (r + 1) <= x) r++;
  else if (r * r > x) r--;
  return r;
}

// uniform-index readlane helpers
__device__ inline int rdl(int v, int l) { return __builtin_amdgcn_readlane(v, l); }
__device__ inline u64 rdl64(u64 x, int l) {
  unsigned lo = (unsigned)__builtin_amdgcn_readlane((int)(unsigned)(x & 0xffffffffull), l);
  unsigned hi = (unsigned)__builtin_amdgcn_readlane((int)(unsigned)(x >> 32), l);
  return ((u64)hi << 32) | (u64)lo;
}
// dynamic select from a 128-entry register file split across wave (v0: ids 0-63, v1: 64-127)
__device__ inline int sel2(int v0, int v1, int idx) {
  int x0 = __shfl(v0, idx & 63);
  int x1 = __shfl(v1, idx & 63);
  return (idx < 64) ? x0 : x1;
}
__device__ inline u64 shfl_xor64(u64 x, int m) {
  int lo = __shfl_xor((int)(unsigned)(x & 0xffffffffull), m);
  int hi = __shfl_xor((int)(unsigned)(x >> 32), m);
  return ((u64)(unsigned)hi << 32) | (u64)(unsigned)lo;
}

// in-wave bitonic compare-exchange (element i = R*64 + lane), N=128 over 2 regs
#define CXL(R, J, K) { \
  u64 vo = shfl_xor64(e##R, J); \
  bool up = (((((R) * 64) & (K)) | (lane & (K))) == 0); \
  bool lower = ((lane & (J)) == 0); \
  bool kmin = (lower == up); \
  u64 mn = (e##R < vo) ? e##R : vo; \
  u64 mx = (e##R < vo) ? vo : e##R; \
  e##R = kmin ? mn : mx; }
#define ALL2(J, K) CXL(0,J,K) CXL(1,J,K)
#define CXR(RA, RB, K) { \
  const bool up = ((((RA) * 64) & (K)) == 0); \
  u64 va = e##RA, vb = e##RB; \
  u64 mn = (va < vb) ? va : vb; \
  u64 mx = (va < vb) ? vb : va; \
  e##RA = up ? mn : mx; e##RB = up ? mx : mn; }

// ---------------- Kernel 1: DTM (hybrid interpolation search) + out-zero ----------------
__global__ __launch_bounds__(1024) void dtm_kernel(const float* __restrict__ win,
                                                   float* __restrict__ fout,
                                                   float* __restrict__ out) {
  __shared__ float P0[64][65];
  __shared__ float P1[64][65];
  __shared__ float P2[64][65];
  int b = blockIdx.y;
  const float* w = win + b * NPTS;
  int tid = threadIdx.x, lane = tid & 63, wv = tid >> 6;

  if (blockIdx.x == 0 && blockIdx.y == 0 && tid < 50) out[20 + tid] = 0.f;  // signal accum base

  for (int rr = 0; rr < 4; ++rr) {
    int r = (wv << 2) | rr;
    float x0 = w[(r << 6) | lane];
    float fl = (float)lane;
    float x1 = x0 * fl, x2 = x1 * fl;
    for (int d = 1; d < 64; d <<= 1) {
      float t0 = __shfl_up(x0, d);
      float t1 = __shfl_up(x1, d);
      float t2 = __shfl_up(x2, d);
      if (lane >= d) { x0 += t0; x1 += t1; x2 += t2; }
    }
    P0[r][lane] = x0; P1[r][lane] = x1; P2[r][lane] = x2;
  }
  __syncthreads();

  float sumw = waveSum(P0[lane][63]);
  float thr = M0f * sumw;

  int q = blockIdx.x * 16 + wv;
  int qi = q >> 6, qj = q & 63;
  int di = qi - lane;
  int disq = di * di;

  auto evalF = [&](int K) -> float {
    float s0 = 0.f;
    int rem = K - disq;
    if (rem >= 0) {
      int r = isqrt_i(rem);
      int l0 = qj - r; l0 = l0 < 0 ? 0 : l0;
      int h0 = qj + r; h0 = h0 > 63 ? 63 : h0;
      s0 = P0[lane][h0] - (l0 > 0 ? P0[lane][l0 - 1] : 0.f);
    }
    return waveSum(s0);
  };

  // hybrid interpolation/bisection: invariant Flo < thr <= Fhi; bisect every 2nd probe
  int lo = -1, hi = KMAXD2;
  float Flo = 0.f, Fhi = sumw;
  int itc = 0;
  while (hi - lo > 1 && itc < 40) {
    int mid;
    if (itc & 1) {
      mid = (lo + hi) >> 1;
    } else {
      float t = (thr - Flo) / fmaxf(Fhi - Flo, 1e-30f);
      mid = lo + (int)(t * (float)(hi - lo));
      mid = mid < lo + 1 ? lo + 1 : (mid > hi - 1 ? hi - 1 : mid);
    }
    float F = evalF(mid);
    if (F >= thr) { hi = mid; Fhi = F; } else { lo = mid; Flo = F; }
    ++itc;
  }
  int kstar = hi;
  float Fm = Flo;

  float g = 0.f;
  {
    int rem = (kstar - 1) - disq;
    if (rem >= 0) {
      int r = isqrt_i(rem);
      int l0 = qj - r; l0 = l0 < 0 ? 0 : l0;
      int h0 = qj + r; h0 = h0 > 63 ? 63 : h0;
      float S0 = P0[lane][h0] - (l0 > 0 ? P0[lane][l0 - 1] : 0.f);
      float S1 = P1[lane][h0] - (l0 > 0 ? P1[lane][l0 - 1] : 0.f);
      float S2 = P2[lane][h0] - (l0 > 0 ? P2[lane][l0 - 1] : 0.f);
      float fq = (float)qj;
      g = (float)disq * S0 + fq * fq * S0 - 2.f * fq * S1 + S2;
    }
  }
  float G = waveSum(g);
  float val = (G + (thr - Fm) * (float)kstar) / thr;
  val = val < 0.f ? 0.f : val;
  float res = (224.f / 63.f) * sqrtf(val);
  if (lane == 0) fout[b * NPTS + q] = res;
}

// ---------------- Kernel 2: fused PH0 (Boruvka) + landscape + MLP ----------------
__global__ __launch_bounds__(1024) void ph_fused(const float* __restrict__ fin,
                                                 const float* __restrict__ Wg,
                                                 const float* __restrict__ bg,
                                                 const float* __restrict__ Wfc,
                                                 const float* __restrict__ bfc,
                                                 float* __restrict__ out) {
  __shared__ __align__(16) float sf[NPTS];
  __shared__ __align__(16) int srep[NPTS];    // aliased later: unsigned ptable[4096]
  __shared__ __align__(16) int sbasin[NPTS];  // aliased later: u64 slist2[SORTCAP]
  __shared__ float smu[128];
  __shared__ int sminv[128];
  __shared__ float2 spairs[PAIRCAP];
  __shared__ float sland[50];
  __shared__ float sx[50];
  __shared__ __align__(16) float sWg[2500];
  __shared__ float sbg[50];
  __shared__ __align__(16) float sWfc[500];
  __shared__ float sbfc[10];
  __shared__ int comparr[128];
  __shared__ u64 minKey[128];
  __shared__ u64 mstlist[MSTCAP];
  __shared__ int c_m, c_np, c_hook, c_chg;
  __shared__ unsigned fminb, fmaxb;
  __shared__ int c_l2;

  int b = blockIdx.x;
  int tid = threadIdx.x;
  int lane = tid & 63;
  if (tid == 0) { c_m = 0; c_l2 = 0; c_np = 0; c_chg = 0; c_hook = 1; fminb = 0x7f800000u; fmaxb = 0u; }
  if (tid < 128) { smu[tid] = 3.0e38f; sminv[tid] = tid; mstlist[tid] = ~0ull; }

  // weight prefetch, vectorized (consumed at the end)
  if (tid < 625) ((float4*)sWg)[tid] = ((const float4*)Wg)[tid];
  if (tid < 125) ((float4*)sWfc)[tid] = ((const float4*)Wfc)[tid];
  if (tid < 50) sbg[tid] = bg[tid];
  if (tid >= 64 && tid < 74) sbfc[tid - 64] = bfc[tid - 64];

  // load f (float4), per-wave min/max
  {
    float4 v4 = ((const float4*)(fin + b * NPTS))[tid];
    ((float4*)sf)[tid] = v4;
    float lmin = fminf(fminf(v4.x, v4.y), fminf(v4.z, v4.w));
    float lmax = fmaxf(fmaxf(v4.x, v4.y), fmaxf(v4.z, v4.w));
    for (int m = 32; m >= 1; m >>= 1) {
      lmin = fminf(lmin, __shfl_xor(lmin, m));
      lmax = fmaxf(lmax, __shfl_xor(lmax, m));
    }
    if (lane == 0) {
      atomicMin(&fminb, __float_as_uint(lmin));
      atomicMax(&fmaxb, __float_as_uint(lmax));
    }
  }
  __syncthreads();

  // steepest-descent pointers
  int preg[4];
#pragma unroll 4
  for (int s = 0; s < 4; ++s) {
    int v = tid + s * 1024;
    int vi = v >> 6, vj = v & 63;
    float bf = sf[v]; int bi = v;
    if (vj > 0)  { float fn = sf[v - 1];  int n = v - 1;  if (fn < bf || (fn == bf && n < bi)) { bf = fn; bi = n; } }
    if (vj < 63) { float fn = sf[v + 1];  int n = v + 1;  if (fn < bf || (fn == bf && n < bi)) { bf = fn; bi = n; } }
    if (vi > 0)  { float fn = sf[v - 64]; int n = v - 64; if (fn < bf || (fn == bf && n < bi)) { bf = fn; bi = n; } }
    if (vi < 63) { float fn = sf[v + 64]; int n = v + 64; if (fn < bf || (fn == bf && n < bi)) { bf = fn; bi = n; } }
    srep[v] = bi;
    preg[s] = bi;
  }
  __syncthreads();

  // pointer jumping, double-hop, early-exit via round-stamped flag (benign same-value races)
  for (int it = 0; it < 8; ++it) {
    bool ch = false;
#pragma unroll 4
    for (int s = 0; s < 4; ++s) {
      int x = srep[preg[s]];
      x = srep[x];
      ch |= (x != preg[s]);
      srep[tid + s * 1024] = x;
      preg[s] = x;
    }
    u64 bl = __ballot(ch);
    if (lane == 0 && bl != 0ull) c_chg = it + 1;
    __syncthreads();
    if (c_chg != it + 1) break;   // nobody changed this round -> all at roots
  }

  // compact basin ids at minima
  for (int v = tid; v < NPTS; v += 1024) {
    if (srep[v] == v) {
      int id = atomicAdd(&c_m, 1);
      if (id < IDCAP) { sbasin[v] = id; smu[id] = sf[v]; sminv[id] = v; }
      else sbasin[v] = IDCAP - 1;
    }
  }
  __syncthreads();
  for (int v = tid; v < NPTS; v += 1024) {
    if (srep[v] != v) sbasin[v] = sbasin[srep[v]];
  }
  __syncthreads();   // srep dead

  // dedup via triangular pair table (aliases srep)
  unsigned* ptable = (unsigned*)srep;
  for (int i = tid; i < 4096; i += 1024) ptable[i] = 0xFFFFFFFFu;
  __syncthreads();
  for (int e = tid; e < NEDGE; e += 1024) {
    int u, v2;
    if (e < 4032) { int i = e / 63; int j = e - i * 63; u = (i << 6) | j; v2 = u + 1; }
    else          { int e2 = e - 4032; u = e2; v2 = u + 64; }
    int bu = sbasin[u], bv = sbasin[v2];
    if (bu != bv) {
      float wgt = fmaxf(sf[u], sf[v2]);
      int a = bu < bv ? bu : bv, bb2 = bu < bv ? bv : bu;
      int t = (bb2 * (bb2 - 1)) / 2 + a;
      atomicMin(&ptable[t], __float_as_uint(wgt));
    }
  }
  __syncthreads();   // sbasin dead

  // compact table -> slist2 (aliases sbasin): (w<<32) | (b<<8) | a
  u64* slist2 = (u64*)sbasin;
  for (int t = tid; t < 4096; t += 1024) {
    unsigned wv2 = ptable[t];
    if (wv2 != 0xFFFFFFFFu) {
      int bb2 = (int)((1.0f + sqrtf(1.0f + 8.0f * (float)t)) * 0.5f);
      while (bb2 > 1 && (bb2 * (bb2 - 1)) / 2 > t) bb2--;
      while (((bb2 + 1) * bb2) / 2 <= t) bb2++;
      int aa = t - (bb2 * (bb2 - 1)) / 2;
      int slot = atomicAdd(&c_l2, 1);
      if (slot < SORTCAP) slist2[slot] = ((u64)wv2 << 32) | (unsigned)((bb2 << 8) | aa);
    }
  }
  // pre-Boruvka init (comparr identity, minKey empty) fused with this barrier
  if (tid < 128) { comparr[tid] = tid; minKey[tid] = ~0ull; }
  __syncthreads();
  int n2 = c_l2; if (n2 > SORTCAP) n2 = SORTCAP;

  // ---- Boruvka contraction, 2 barriers/round; min-edge via u64 atomicMin on (w, edge_idx) ----
  int comp0 = lane, comp1 = 64 + lane;   // meaningful in wave0 only
  int nmst = 0;
  for (int round = 0; round < 7; ++round) {
    for (int e = tid; e < n2; e += 1024) {
      u64 ev = slist2[e];
      int a = (int)(ev & 0xffull), bb2 = (int)((ev >> 8) & 0xffull);
      int ra = comparr[a], rb = comparr[bb2];
      if (ra != rb) {
        u64 key = (ev & 0xFFFFFFFF00000000ull) | (u64)(unsigned)e;  // (w, idx): total order
        atomicMin(&minKey[ra], key);
        atomicMin(&minKey[rb], key);
      }
    }
    __syncthreads();
    if (tid < 64) {
      u64 k0 = minKey[lane], k1 = minKey[64 + lane];
      unsigned mi0 = (k0 != ~0ull) ? (unsigned)(k0 & 0xffffffffull) : 0xFFFFFFFFu;
      unsigned mi1 = (k1 != ~0ull) ? (unsigned)(k1 & 0xffffffffull) : 0xFFFFFFFFu;
      u64 ev0 = (mi0 != 0xFFFFFFFFu) ? slist2[mi0] : 0ull;
      u64 ev1 = (mi1 != 0xFFFFFFFFu) ? slist2[mi1] : 0ull;
      int a0 = (int)(ev0 & 0xffull), b0 = (int)((ev0 >> 8) & 0xffull);
      int a1 = (int)(ev1 & 0xffull), b1 = (int)((ev1 >> 8) & 0xffull);
      int raA = sel2(comp0, comp1, a0), rbA = sel2(comp0, comp1, b0);
      int raB = sel2(comp0, comp1, a1), rbB = sel2(comp0, comp1, b1);
      int parA0 = (mi0 != 0xFFFFFFFFu) ? ((raA == lane) ? rbA : raA) : lane;
      int parA1 = (mi1 != 0xFFFFFFFFu) ? ((raB == 64 + lane) ? rbB : raB) : (64 + lane);
      // 2-cycle resolve (distinct (w,idx) keys => only 2-cycles possible)
      int pp0 = sel2(parA0, parA1, parA0);
      int pp1 = sel2(parA0, parA1, parA1);
      int par0 = (pp0 == lane && lane < parA0) ? lane : parA0;
      int par1 = (pp1 == (64 + lane) && (64 + lane) < parA1) ? (64 + lane) : parA1;
      // collect MST edges: only hooking (non-root) endpoints collect -> each edge once, total <= IDCAP-1
      bool h0 = (par0 != lane);
      bool h1 = (par1 != (64 + lane));
      u64 mlo = __ballot(h0);
      int cnt0 = __popcll(mlo);
      int pos0 = nmst + __popcll(mlo & ((1ull << lane) - 1ull));
      if (h0 && pos0 < MSTCAP) mstlist[pos0] = ev0;
      u64 mhi = __ballot(h1);
      int pos1 = nmst + cnt0 + __popcll(mhi & ((1ull << lane) - 1ull));
      if (h1 && pos1 < MSTCAP) mstlist[pos1] = ev1;
      int tot = cnt0 + __popcll(mhi);
      nmst += tot;
      if (lane == 0) c_hook = (tot > 0);
      // compress par, then update comp; write comparr + re-init minKey for next round
      for (int j = 0; j < 7; ++j) {
        int n0 = sel2(par0, par1, par0);
        int n1 = sel2(par0, par1, par1);
        bool chp = (n0 != par0) || (n1 != par1);
        par0 = n0; par1 = n1;
        if (__ballot(chp) == 0ull) break;
      }
      comp0 = sel2(par0, par1, comp0);
      comp1 = sel2(par0, par1, comp1);
      comparr[lane] = comp0; comparr[64 + lane] = comp1;
      minKey[lane] = ~0ull; minKey[64 + lane] = ~0ull;
    }
    __syncthreads();
    if (c_hook == 0) break;
  }
  if (nmst > MSTCAP) nmst = MSTCAP;

  // ---- wave0: in-register sort (N=128, 2 regs, zero barriers) + packed-state readlane Kruskal ----
  if (tid < 64) {
    u64 e0 = mstlist[lane], e1 = mstlist[64 + lane];
    ALL2(1,2)
    ALL2(2,4) ALL2(1,4)
    ALL2(4,8) ALL2(2,8) ALL2(1,8)
    ALL2(8,16) ALL2(4,16) ALL2(2,16) ALL2(1,16)
    ALL2(16,32) ALL2(8,32) ALL2(4,32) ALL2(2,32) ALL2(1,32)
    ALL2(32,64) ALL2(16,64) ALL2(8,64) ALL2(4,64) ALL2(2,64) ALL2(1,64)
    CXR(0,1,128)
    ALL2(32,128) ALL2(16,128) ALL2(8,128) ALL2(4,128) ALL2(2,128) ALL2(1,128)

    // packed union-find state per id: (mu_bits<<32) | (rv<<13) | p
    u64 st0 = ((u64)__float_as_uint(smu[lane]) << 32) | ((u64)(unsigned)sminv[lane] << 13) | (unsigned)lane;
    u64 st1 = ((u64)__float_as_uint(smu[64 + lane]) << 32) | ((u64)(unsigned)sminv[64 + lane] << 13) | (unsigned)(64 + lane);
    int np = 0;
#define KBLK(R, BASE) \
    for (int s = 0; s < 64; ++s) { \
      if (BASE + s >= nmst) break; \
      u64 ev = rdl64(e##R, s); \
      int a = (int)(ev & 0xffull), bb2 = (int)((ev >> 8) & 0xffull); \
      int ia = a & 63, ib = bb2 & 63; \
      u64 stA = (a < 64) ? rdl64(st0, ia) : rdl64(st1, ia); \
      u64 stB = (bb2 < 64) ? rdl64(st0, ib) : rdl64(st1, ib); \
      int pa = (int)(stA & 127ull), pb = (int)(stB & 127ull); \
      if (pa == pb) continue; \
      bool aeld = (stA >> 13) < (stB >> 13); \
      u64 stE = aeld ? stA : stB; \
      u64 stY = aeld ? stB : stA; \
      unsigned yng = (unsigned)(stY & 127ull); \
      float byoung = __uint_as_float((unsigned)(stY >> 32)); \
      bool g0 = ((unsigned)(st0 & 127ull) == yng); st0 = g0 ? stE : st0; \
      bool g1 = ((unsigned)(st1 & 127ull) == yng); st1 = g1 ? stE : st1; \
      if (lane == 0 && np < PAIRCAP - 1) spairs[np] = make_float2(byoung, __uint_as_float((unsigned)(ev >> 32))); \
      np++; \
    }
    KBLK(0, 0) KBLK(1, 64)
#undef KBLK
    if (np > PAIRCAP - 1) np = PAIRCAP - 1;
    if (lane == 0) {
      spairs[np] = make_float2(__uint_as_float(fminb), __uint_as_float(fmaxb));  // essential pair
      c_np = np + 1;
    }
  }
  __syncthreads();

  // landscape (top-2 triangles at 25 t's)
  int totp = c_np;
  if (tid < 25) {
    float tv = 1.875f * (float)tid;
    float top1 = 0.f, top2 = 0.f;
    for (int i = 0; i < totp; ++i) {
      float2 p = spairs[i];
      float tri = fminf(tv - p.x, p.y - tv);
      tri = fmaxf(tri, 0.f);
      if (tri > top1) { top2 = top1; top1 = tri; }
      else if (tri > top2) top2 = tri;
    }
    sland[tid] = top1;
    sland[25 + tid] = top2;
  }
  __syncthreads();

  // x = land @ Wg.T + bg
  if (tid < 50) {
    float acc = sbg[tid];
    for (int k = 0; k < 50; ++k) acc += sland[k] * sWg[tid * 50 + k];
    sx[tid] = acc;
  }
  __syncthreads();

  // outputs
  if (tid < 50) atomicAdd(&out[20 + tid], fabsf(sx[tid]));
  if (tid >= 64 && tid < 74) {
    int c = tid - 64;
    float acc = sbfc[c];
    for (int o = 0; o < 50; ++o) acc += fmaxf(sx[o], 0.f) * sWfc[c * 50 + o];
    out[b * 10 + c] = acc;
  }
}

extern "C" void kernel_launch(void* const* d_in, const int* in_sizes, int n_in,
                              void* d_out, int out_size, void* d_ws, size_t ws_size,
                              hipStream_t stream) {
  (void)in_sizes; (void)n_in; (void)out_size; (void)ws_size;
  const float* input = (const float*)d_in[0];
  const float* Wg  = (const float*)d_in[1];
  const float* bg  = (const float*)d_in[2];
  const float* Wfc = (const float*)d_in[3];
  const float* bfc = (const float*)d_in[4];
  float* out = (float*)d_out;

  float* f_ws = (float*)d_ws;  // 2*4096 f32

  dtm_kernel<<<dim3(256, 2), 1024, 0, stream>>>(input, f_ws, out);
  ph_fused<<<dim3(2), 1024, 0, stream>>>(f_ws, Wg, bg, Wfc, bfc, out);
}